// Round 8
// baseline (65.690 us; speedup 1.0000x reference)
//
#include <hip/hip_runtime.h>
#include <float.h>
#include <stdint.h>

#define N_TOKENS 65536
#define N_EMB    1024
#define DIM      256

typedef __attribute__((ext_vector_type(4))) float f32x4;

// v_cvt_pk_fp8_f32: packs 2 floats as OCP e4m3 into 16-bit half of `old`.
// HI must be a compile-time constant (ISA immediate).
template <bool HI>
__device__ __forceinline__ unsigned pk8(float a, float b, unsigned old) {
    return (unsigned)__builtin_amdgcn_cvt_pk_fp8_f32(a, b, (int)old, HI);
}

// async global->LDS, 16B per lane (dest = wave-uniform base + lane*16)
__device__ __forceinline__ void gld_lds16(const void* g, void* l) {
    __builtin_amdgcn_global_load_lds(
        (__attribute__((address_space(1))) void*)(g),
        (__attribute__((address_space(3))) void*)(l), 16, 0, 0);
}

// ---------------- kernel 1: codebook row squared-norms (UNCHANGED) ----------------
__global__ __launch_bounds__(256) void cnorm_kernel(const float* __restrict__ cb,
                                                    float* __restrict__ cn2) {
    int gwave = (blockIdx.x * 256 + threadIdx.x) >> 6;
    int lane  = threadIdx.x & 63;
    if (gwave >= N_EMB) return;
    float4 v = ((const float4*)cb)[gwave * 64 + lane];
    float s = v.x * v.x + v.y * v.y + v.z * v.z + v.w * v.w;
#pragma unroll
    for (int m = 1; m < 64; m <<= 1) s += __shfl_xor(s, m);
    if (lane == 0) cn2[gwave] = s;
}

// ---------------- kernel 2: codebook -> fp8 (x512) pre-swizzled LDS image ----------------
// granule (16B) = lane fragment-pair: tile T, phase ph = sp*2+half, lane ln.
// code = T*32 + half*16 + (ln&15), g = ln>>4.
// bytes 0-7  : slice 2sp   -> k = sp*64      + g*8 + j
// bytes 8-15 : slice 2sp+1 -> k = sp*64 + 32 + g*8 + j
// Staging AND compute reads are lane-linear -> 0 conflicts, no XOR swizzle.
__global__ __launch_bounds__(256) void cbimg_kernel(const float* __restrict__ cb,
                                                    unsigned char* __restrict__ img) {
    int gid = blockIdx.x * 256 + threadIdx.x;     // 16384 granules
    int T = gid >> 9, G = gid & 511;
    int ln = G & 63, ph = G >> 6;
    int sp = ph >> 1, half = ph & 1;
    int c = half * 16 + (ln & 15), g = ln >> 4;
    const float* p = cb + (size_t)(T * 32 + c) * DIM + sp * 64 + g * 8;
    float4 x0 = *(const float4*)p;
    float4 x1 = *(const float4*)(p + 4);
    float4 y0 = *(const float4*)(p + 32);
    float4 y1 = *(const float4*)(p + 36);
    uint4 o;
    unsigned w;
    w = pk8<false>(512.f * x0.x, 512.f * x0.y, 0); o.x = pk8<true>(512.f * x0.z, 512.f * x0.w, w);
    w = pk8<false>(512.f * x1.x, 512.f * x1.y, 0); o.y = pk8<true>(512.f * x1.z, 512.f * x1.w, w);
    w = pk8<false>(512.f * y0.x, 512.f * y0.y, 0); o.z = pk8<true>(512.f * y0.z, 512.f * y0.w, w);
    w = pk8<false>(512.f * y1.x, 512.f * y1.y, 0); o.w = pk8<true>(512.f * y1.z, 512.f * y1.w, w);
    ((uint4*)img)[gid] = o;
}

// ---------------- kernel 3: fully fused VQ, fp8 MFMA, triple-buffered pipeline ----------
// 512 blocks x 256 thr (4 waves), 32 tokens/wave. A = fp8(-64*z) in regs (32 VGPR),
// B (x512) tiles 8KB via global_load_lds. score = cn + acc * 2^-14  (= cn - 2*dot).
__global__ __launch_bounds__(256, 2) void fused_vq_kernel(
        const float* __restrict__ z, const unsigned char* __restrict__ cbimg,
        const float* __restrict__ cb, const float* __restrict__ cn2,
        float* __restrict__ out, float* __restrict__ partials) {
    __shared__ long2 BsV[3][512];                 // 3 x 8KB
    __shared__ float cnS[N_EMB];                  // 4KB
    __shared__ int   winS[128];
    __shared__ float distS[128];
    __shared__ float xnS[128];
    const int t = threadIdx.x;
    const int lane = t & 63, w = t >> 6;
    const int col = lane & 15, g = lane >> 4;

    const char* srcL = (const char*)cbimg + w * 2048 + lane * 16;
    char* q0 = (char*)&BsV[0][0] + w * 2048;      // wave quarter of each buffer
    char* q1 = (char*)&BsV[1][0] + w * 2048;
    char* q2 = (char*)&BsV[2][0] + w * 2048;

    // prologue: issue tiles 0 and 1 (2 loads each)
    gld_lds16(srcL,        q0);
    gld_lds16(srcL + 1024, q0 + 1024);
    gld_lds16(srcL + 8192,        q1);
    gld_lds16(srcL + 8192 + 1024, q1 + 1024);

    // A: 32 tokens/wave as fp8(-64*z); xn accumulated in fp32
    long  ah[2][8];
    float xnp[2] = {0.f, 0.f};
    const int rbase = blockIdx.x * 128 + w * 32 + col;
#pragma unroll
    for (int m = 0; m < 2; ++m) {
#pragma unroll
        for (int s = 0; s < 8; ++s) {
            const float* p = z + (size_t)(rbase + m * 16) * DIM + s * 32 + g * 8;
            float4 x0 = *(const float4*)p;
            float4 x1 = *(const float4*)(p + 4);
            xnp[m] = fmaf(x0.x, x0.x, xnp[m]); xnp[m] = fmaf(x0.y, x0.y, xnp[m]);
            xnp[m] = fmaf(x0.z, x0.z, xnp[m]); xnp[m] = fmaf(x0.w, x0.w, xnp[m]);
            xnp[m] = fmaf(x1.x, x1.x, xnp[m]); xnp[m] = fmaf(x1.y, x1.y, xnp[m]);
            xnp[m] = fmaf(x1.z, x1.z, xnp[m]); xnp[m] = fmaf(x1.w, x1.w, xnp[m]);
            unsigned w0, w1;
            w0 = pk8<false>(-64.f * x0.x, -64.f * x0.y, 0);
            w0 = pk8<true> (-64.f * x0.z, -64.f * x0.w, w0);
            w1 = pk8<false>(-64.f * x1.x, -64.f * x1.y, 0);
            w1 = pk8<true> (-64.f * x1.z, -64.f * x1.w, w1);
            ah[m][s] = (long)((((unsigned long long)w1) << 32) | w0);
        }
    }
#pragma unroll
    for (int m = 0; m < 2; ++m) {
        xnp[m] += __shfl_xor(xnp[m], 16);
        xnp[m] += __shfl_xor(xnp[m], 32);
        if (g == 0) xnS[w * 32 + m * 16 + col] = xnp[m];
    }
#pragma unroll
    for (int i = 0; i < 4; ++i) cnS[t + i * 256] = cn2[t + i * 256];

    float best[2][4];
    int   bidx[2][4];
#pragma unroll
    for (int m = 0; m < 2; ++m)
#pragma unroll
        for (int r = 0; r < 4; ++r) { best[m][r] = FLT_MAX; bidx[m][r] = 0; }

    // make cnS/xnS ds_writes visible before the first raw barrier
    asm volatile("s_waitcnt lgkmcnt(0)" ::: "memory");

    const char* rd0 = (const char*)&BsV[0][0];
    const char* rd1 = (const char*)&BsV[1][0];
    const char* rd2 = (const char*)&BsV[2][0];
    char *wq0 = q0, *wq1 = q1, *wq2 = q2;

    for (int T = 0; T < 32; ++T) {
        if (T < 31) asm volatile("s_waitcnt vmcnt(2)" ::: "memory");
        else        asm volatile("s_waitcnt vmcnt(0)" ::: "memory");
        __builtin_amdgcn_s_barrier();             // all waves: tile T resident
        __builtin_amdgcn_sched_barrier(0);
        if (T + 2 < 32) {                         // issue tile T+2 (buffer read at T-1)
            const char* s2 = srcL + (T + 2) * 8192;
            gld_lds16(s2,        wq2);
            gld_lds16(s2 + 1024, wq2 + 1024);
        }
        const f32x4 zero4 = {0.f, 0.f, 0.f, 0.f};
        f32x4 acc[2][2] = {{zero4, zero4}, {zero4, zero4}};
        __builtin_amdgcn_s_setprio(1);
#pragma unroll
        for (int sp = 0; sp < 4; ++sp) {
            long2 b0 = *(const long2*)(rd0 + (sp * 2 + 0) * 1024 + (lane << 4));
            long2 b1 = *(const long2*)(rd0 + (sp * 2 + 1) * 1024 + (lane << 4));
            acc[0][0] = __builtin_amdgcn_mfma_f32_16x16x32_fp8_fp8(ah[0][2*sp],   b0.x, acc[0][0], 0, 0, 0);
            acc[0][0] = __builtin_amdgcn_mfma_f32_16x16x32_fp8_fp8(ah[0][2*sp+1], b0.y, acc[0][0], 0, 0, 0);
            acc[1][0] = __builtin_amdgcn_mfma_f32_16x16x32_fp8_fp8(ah[1][2*sp],   b0.x, acc[1][0], 0, 0, 0);
            acc[1][0] = __builtin_amdgcn_mfma_f32_16x16x32_fp8_fp8(ah[1][2*sp+1], b0.y, acc[1][0], 0, 0, 0);
            acc[0][1] = __builtin_amdgcn_mfma_f32_16x16x32_fp8_fp8(ah[0][2*sp],   b1.x, acc[0][1], 0, 0, 0);
            acc[0][1] = __builtin_amdgcn_mfma_f32_16x16x32_fp8_fp8(ah[0][2*sp+1], b1.y, acc[0][1], 0, 0, 0);
            acc[1][1] = __builtin_amdgcn_mfma_f32_16x16x32_fp8_fp8(ah[1][2*sp],   b1.x, acc[1][1], 0, 0, 0);
            acc[1][1] = __builtin_amdgcn_mfma_f32_16x16x32_fp8_fp8(ah[1][2*sp+1], b1.y, acc[1][1], 0, 0, 0);
        }
        __builtin_amdgcn_s_setprio(0);
        // running per-lane argmin: score = cn + acc * 2^-14  (acc = 32768 * (-dot))
#pragma unroll
        for (int nf = 0; nf < 2; ++nf) {
            int code = T * 32 + nf * 16 + col;
            float cn = cnS[code];
#pragma unroll
            for (int m = 0; m < 2; ++m)
#pragma unroll
                for (int r = 0; r < 4; ++r) {
                    float sc = fmaf(acc[m][nf][r], 6.103515625e-05f, cn);
                    if (sc < best[m][r]) { best[m][r] = sc; bidx[m][r] = code; }
                }
        }
        // rotate buffers
        const char* tr = rd0; rd0 = rd1; rd1 = rd2; rd2 = tr;
        char* tw = wq0; wq0 = wq1; wq1 = wq2; wq2 = tw;
    }

    // merge across the 16 col-lanes; acc row r on lane = token m*16 + g*4 + r
#pragma unroll
    for (int m = 0; m < 2; ++m)
#pragma unroll
        for (int r = 0; r < 4; ++r) {
            float sc = best[m][r];
            int   cd = bidx[m][r];
#pragma unroll
            for (int mask = 1; mask <= 8; mask <<= 1) {
                float os = __shfl_xor(sc, mask);
                int   oc = __shfl_xor(cd, mask);
                if (os < sc || (os == sc && oc < cd)) { sc = os; cd = oc; }
            }
            if (col == 0) {
                int tl = w * 32 + m * 16 + g * 4 + r;
                winS[tl]  = cd;
                distS[tl] = sc;
            }
        }
    __syncthreads();

    // tail A: block loss partial = sum over 128 tokens of (xn + score_win)
    if (t < 64) {
        float s = (xnS[t] + distS[t]) + (xnS[t + 64] + distS[t + 64]);
#pragma unroll
        for (int m = 1; m < 64; m <<= 1) s += __shfl_xor(s, m);
        if (t == 0) partials[blockIdx.x] = s;
    }
    // tail B: output = codebook[winner] (wave reads one cb row / iter, coalesced)
    const size_t ob = (size_t)blockIdx.x * 8192;  // float4 units
#pragma unroll 4
    for (int i = 0; i < 32; ++i) {
        int f = i * 256 + t;
        int tl = f >> 6, c4 = f & 63;
        float4 q = ((const float4*)cb)[winS[tl] * 64 + c4];
        ((float4*)out)[ob + f] = q;
    }
}

// ---------------- kernel 4: deterministic partial reduction (512 partials) ----------------
__global__ __launch_bounds__(256) void reduce_kernel(const float* __restrict__ partials,
                                                     float* __restrict__ out_loss) {
    const int tid = threadIdx.x;
    float s = partials[tid] + partials[tid + 256];
#pragma unroll
    for (int m = 1; m < 64; m <<= 1) s += __shfl_xor(s, m);
    __shared__ float wsum[4];
    if ((tid & 63) == 0) wsum[tid >> 6] = s;
    __syncthreads();
    if (tid == 0) *out_loss = 2.0f * ((wsum[0] + wsum[1]) + (wsum[2] + wsum[3]));
}

extern "C" void kernel_launch(void* const* d_in, const int* in_sizes, int n_in,
                              void* d_out, int out_size, void* d_ws, size_t ws_size,
                              hipStream_t stream) {
    const float* z  = (const float*)d_in[0];   // z_e       [65536,256]
    const float* cb = (const float*)d_in[1];   // codebook  [1024,256]
    float* out = (float*)d_out;
    char*  ws  = (char*)d_ws;

    float*         cn2      = (float*)(ws);                    // 4 KB
    float*         partials = (float*)(ws + 4096);             // 2 KB
    unsigned char* cbimg    = (unsigned char*)(ws + 8192);     // 256 KB

    cnorm_kernel   <<<256, 256, 0, stream>>>(cb, cn2);
    cbimg_kernel   <<<64, 256, 0, stream>>>(cb, cbimg);
    fused_vq_kernel<<<512, 256, 0, stream>>>(z, cbimg, cb, cn2, out, partials);
    reduce_kernel  <<<1, 256, 0, stream>>>(partials, out + (size_t)N_TOKENS * DIM);
}

// Round 9
// 57.242 us; speedup vs baseline: 1.1476x; 1.1476x over previous
//
#include <hip/hip_runtime.h>
#include <float.h>
#include <stdint.h>

#define N_TOKENS 65536
#define N_EMB    1024
#define DIM      256

typedef __attribute__((ext_vector_type(4))) float f32x4;

// v_cvt_pk_fp8_f32: packs 2 floats as OCP e4m3 into 16-bit half of `old`.
// HI must be a compile-time constant (ISA immediate).
template <bool HI>
__device__ __forceinline__ unsigned pk8(float a, float b, unsigned old) {
    return (unsigned)__builtin_amdgcn_cvt_pk_fp8_f32(a, b, (int)old, HI);
}

// ---------------- kernel 1: codebook row squared-norms (UNCHANGED) ----------------
__global__ __launch_bounds__(256) void cnorm_kernel(const float* __restrict__ cb,
                                                    float* __restrict__ cn2) {
    int gwave = (blockIdx.x * 256 + threadIdx.x) >> 6;
    int lane  = threadIdx.x & 63;
    if (gwave >= N_EMB) return;
    float4 v = ((const float4*)cb)[gwave * 64 + lane];
    float s = v.x * v.x + v.y * v.y + v.z * v.z + v.w * v.w;
#pragma unroll
    for (int m = 1; m < 64; m <<= 1) s += __shfl_xor(s, m);
    if (lane == 0) cn2[gwave] = s;
}

// ---------------- kernel 2: codebook -> fp8 (x512) fragment image (UNCHANGED layout) --------
// granule (16B) = lane fragment-pair: tile T, phase ph = sp*2+half, lane ln.
// code = T*32 + half*16 + (ln&15), g = ln>>4.
// bytes 0-7  : k = sp*64      + g*8 + j   (K-window 2sp)
// bytes 8-15 : k = sp*64 + 32 + g*8 + j   (K-window 2sp+1)
__global__ __launch_bounds__(256) void cbimg_kernel(const float* __restrict__ cb,
                                                    unsigned char* __restrict__ img) {
    int gid = blockIdx.x * 256 + threadIdx.x;     // 16384 granules
    int T = gid >> 9, G = gid & 511;
    int ln = G & 63, ph = G >> 6;
    int sp = ph >> 1, half = ph & 1;
    int c = half * 16 + (ln & 15), g = ln >> 4;
    const float* p = cb + (size_t)(T * 32 + c) * DIM + sp * 64 + g * 8;
    float4 x0 = *(const float4*)p;
    float4 x1 = *(const float4*)(p + 4);
    float4 y0 = *(const float4*)(p + 32);
    float4 y1 = *(const float4*)(p + 36);
    uint4 o;
    unsigned w;
    w = pk8<false>(512.f * x0.x, 512.f * x0.y, 0); o.x = pk8<true>(512.f * x0.z, 512.f * x0.w, w);
    w = pk8<false>(512.f * x1.x, 512.f * x1.y, 0); o.y = pk8<true>(512.f * x1.z, 512.f * x1.w, w);
    w = pk8<false>(512.f * y0.x, 512.f * y0.y, 0); o.z = pk8<true>(512.f * y0.z, 512.f * y0.w, w);
    w = pk8<false>(512.f * y1.x, 512.f * y1.y, 0); o.w = pk8<true>(512.f * y1.z, 512.f * y1.w, w);
    ((uint4*)img)[gid] = o;
}

// ---------------- kernel 3: fused VQ — single-wave blocks, barrier-free, reg-streamed B -----
// 2048 blocks x 64 thr (1 wave), 32 tokens/wave. A = fp8(-64*z) in regs.
// B fragments stream L2 -> VGPR (double-buffered bA/bB, compiler-counted vmcnt).
// No LDS staging, no s_barrier. 8 self-paced waves/CU overlap A/K/out phases.
__global__ __launch_bounds__(64, 2) void fused_vq_kernel(
        const float* __restrict__ z, const unsigned char* __restrict__ cbimg,
        const float* __restrict__ cb, const float* __restrict__ cn2,
        float* __restrict__ out, float* __restrict__ partials) {
    __shared__ int   winS[32];
    __shared__ float distS[32];
    __shared__ float xnS[32];
    const int t = threadIdx.x;                    // 0..63
    const int col = t & 15, g = t >> 4;

    // ---- B prologue: issue tiles 0,1 into registers (earliest issue) ----
    long2 bA[8], bB[8];
    float cnA0, cnA1, cnB0, cnB1;
    auto LOADT = [&](long2* b, float& c0, float& c1, int T) {
        const long2* src = (const long2*)(cbimg + (size_t)T * 8192) + t;
#pragma unroll
        for (int ph = 0; ph < 8; ++ph) b[ph] = src[ph * 64];
        c0 = cn2[T * 32 + col];
        c1 = cn2[T * 32 + 16 + col];
    };
    LOADT(bA, cnA0, cnA1, 0);
    LOADT(bB, cnB0, cnB1, 1);

    // ---- A: load+convert 32 tokens (fp8(-64*z)); xn in fp32 ----
    long  ah[2][8];
    float xnp[2] = {0.f, 0.f};
    const int rbase = blockIdx.x * 32 + col;
#pragma unroll
    for (int m = 0; m < 2; ++m) {
#pragma unroll
        for (int s = 0; s < 8; ++s) {
            const float* p = z + (size_t)(rbase + m * 16) * DIM + s * 32 + g * 8;
            float4 x0 = *(const float4*)p;
            float4 x1 = *(const float4*)(p + 4);
            xnp[m] = fmaf(x0.x, x0.x, xnp[m]); xnp[m] = fmaf(x0.y, x0.y, xnp[m]);
            xnp[m] = fmaf(x0.z, x0.z, xnp[m]); xnp[m] = fmaf(x0.w, x0.w, xnp[m]);
            xnp[m] = fmaf(x1.x, x1.x, xnp[m]); xnp[m] = fmaf(x1.y, x1.y, xnp[m]);
            xnp[m] = fmaf(x1.z, x1.z, xnp[m]); xnp[m] = fmaf(x1.w, x1.w, xnp[m]);
            unsigned w0, w1;
            w0 = pk8<false>(-64.f * x0.x, -64.f * x0.y, 0);
            w0 = pk8<true> (-64.f * x0.z, -64.f * x0.w, w0);
            w1 = pk8<false>(-64.f * x1.x, -64.f * x1.y, 0);
            w1 = pk8<true> (-64.f * x1.z, -64.f * x1.w, w1);
            ah[m][s] = (long)((((unsigned long long)w1) << 32) | w0);
        }
    }
#pragma unroll
    for (int m = 0; m < 2; ++m) {                 // complete xn over 4 g-slices
        xnp[m] += __shfl_xor(xnp[m], 16);
        xnp[m] += __shfl_xor(xnp[m], 32);
        if (g == 0) xnS[m * 16 + col] = xnp[m];   // lanes 0-15
    }

    float best[2][4];
    int   bidx[2][4];
#pragma unroll
    for (int m = 0; m < 2; ++m)
#pragma unroll
        for (int r = 0; r < 4; ++r) { best[m][r] = FLT_MAX; bidx[m][r] = 0; }

    // ---- K-loop: compute tile T from regs, reload T+2 (compiler-pipelined) ----
    auto STEP = [&](const long2* b, float c0, float c1, int T) {
        const f32x4 zero4 = {0.f, 0.f, 0.f, 0.f};
        f32x4 a00 = zero4, a01 = zero4, a10 = zero4, a11 = zero4;
#pragma unroll
        for (int sp = 0; sp < 4; ++sp) {
            long2 b0 = b[2 * sp], b1 = b[2 * sp + 1];
            a00 = __builtin_amdgcn_mfma_f32_16x16x32_fp8_fp8(ah[0][2*sp],   b0.x, a00, 0, 0, 0);
            a00 = __builtin_amdgcn_mfma_f32_16x16x32_fp8_fp8(ah[0][2*sp+1], b0.y, a00, 0, 0, 0);
            a10 = __builtin_amdgcn_mfma_f32_16x16x32_fp8_fp8(ah[1][2*sp],   b0.x, a10, 0, 0, 0);
            a10 = __builtin_amdgcn_mfma_f32_16x16x32_fp8_fp8(ah[1][2*sp+1], b0.y, a10, 0, 0, 0);
            a01 = __builtin_amdgcn_mfma_f32_16x16x32_fp8_fp8(ah[0][2*sp],   b1.x, a01, 0, 0, 0);
            a01 = __builtin_amdgcn_mfma_f32_16x16x32_fp8_fp8(ah[0][2*sp+1], b1.y, a01, 0, 0, 0);
            a11 = __builtin_amdgcn_mfma_f32_16x16x32_fp8_fp8(ah[1][2*sp],   b1.x, a11, 0, 0, 0);
            a11 = __builtin_amdgcn_mfma_f32_16x16x32_fp8_fp8(ah[1][2*sp+1], b1.y, a11, 0, 0, 0);
        }
        // score = cn + acc * 2^-14   (acc = 32768 * (-dot)); identical to round 8
#pragma unroll
        for (int nf = 0; nf < 2; ++nf) {
            int   code = T * 32 + nf * 16 + col;
            float cn   = nf ? c1 : c0;
            const f32x4& q0 = nf ? a01 : a00;
            const f32x4& q1 = nf ? a11 : a10;
#pragma unroll
            for (int r = 0; r < 4; ++r) {
                float s0 = fmaf(q0[r], 6.103515625e-05f, cn);
                if (s0 < best[0][r]) { best[0][r] = s0; bidx[0][r] = code; }
                float s1 = fmaf(q1[r], 6.103515625e-05f, cn);
                if (s1 < best[1][r]) { best[1][r] = s1; bidx[1][r] = code; }
            }
        }
    };

    for (int T = 0; T < 32; T += 2) {
        STEP(bA, cnA0, cnA1, T);
        if (T + 2 < 32) LOADT(bA, cnA0, cnA1, T + 2);
        STEP(bB, cnB0, cnB1, T + 1);
        if (T + 3 < 32) LOADT(bB, cnB0, cnB1, T + 3);
    }

    // ---- merge across the 16 col-lanes; token = m*16 + g*4 + r ----
#pragma unroll
    for (int m = 0; m < 2; ++m)
#pragma unroll
        for (int r = 0; r < 4; ++r) {
            float sc = best[m][r];
            int   cd = bidx[m][r];
#pragma unroll
            for (int mask = 1; mask <= 8; mask <<= 1) {
                float os = __shfl_xor(sc, mask);
                int   oc = __shfl_xor(cd, mask);
                if (os < sc || (os == sc && oc < cd)) { sc = os; cd = oc; }
            }
            if (col == 0) {                       // lanes 0,16,32,48
                int tl = m * 16 + g * 4 + r;
                winS[tl]  = cd;
                distS[tl] = sc;
            }
        }
    // single wave: LDS visibility needs only lgkmcnt (compiler inserts); no barrier.

    // ---- loss partial: sum over 32 tokens of (xn + score_win) ----
    {
        float s = (t < 32) ? (xnS[t] + distS[t]) : 0.f;
#pragma unroll
        for (int m = 1; m < 64; m <<= 1) s += __shfl_xor(s, m);
        if (t == 0) partials[blockIdx.x] = s;
    }

    // ---- output: 32 tokens x 1KB, winner row coalesced from L2-hot cb ----
    const size_t ob = (size_t)blockIdx.x * 2048;  // float4 units
#pragma unroll 8
    for (int i = 0; i < 32; ++i) {
        int k = winS[i];                          // wave-uniform
        float4 q = ((const float4*)cb)[k * 64 + t];
        ((float4*)out)[ob + i * 64 + t] = q;
    }
}

// ---------------- kernel 4: deterministic partial reduction (2048 partials) ----------------
__global__ __launch_bounds__(256) void reduce_kernel(const float* __restrict__ partials,
                                                     float* __restrict__ out_loss) {
    const int tid = threadIdx.x;
    float s = 0.f;
#pragma unroll
    for (int u = 0; u < 8; ++u) s += partials[tid + 256 * u];
#pragma unroll
    for (int m = 1; m < 64; m <<= 1) s += __shfl_xor(s, m);
    __shared__ float wsum[4];
    if ((tid & 63) == 0) wsum[tid >> 6] = s;
    __syncthreads();
    if (tid == 0) *out_loss = 2.0f * ((wsum[0] + wsum[1]) + (wsum[2] + wsum[3]));
}

extern "C" void kernel_launch(void* const* d_in, const int* in_sizes, int n_in,
                              void* d_out, int out_size, void* d_ws, size_t ws_size,
                              hipStream_t stream) {
    const float* z  = (const float*)d_in[0];   // z_e       [65536,256]
    const float* cb = (const float*)d_in[1];   // codebook  [1024,256]
    float* out = (float*)d_out;
    char*  ws  = (char*)d_ws;

    float*         cn2      = (float*)(ws);                    // 4 KB
    float*         partials = (float*)(ws + 4096);             // 8 KB
    unsigned char* cbimg    = (unsigned char*)(ws + 16384);    // 256 KB

    cnorm_kernel   <<<256, 256, 0, stream>>>(cb, cn2);
    cbimg_kernel   <<<64, 256, 0, stream>>>(cb, cbimg);
    fused_vq_kernel<<<2048, 64, 0, stream>>>(z, cbimg, cb, cn2, out, partials);
    reduce_kernel  <<<1, 256, 0, stream>>>(partials, out + (size_t)N_TOKENS * DIM);
}

// Round 10
// 53.760 us; speedup vs baseline: 1.2219x; 1.0648x over previous
//
#include <hip/hip_runtime.h>
#include <float.h>
#include <stdint.h>

#define N_TOKENS 65536
#define N_EMB    1024
#define DIM      256

typedef __attribute__((ext_vector_type(4))) float f32x4;

// v_cvt_pk_fp8_f32: packs 2 floats as OCP e4m3 into 16-bit half of `old`.
template <bool HI>
__device__ __forceinline__ unsigned pk8(float a, float b, unsigned old) {
    return (unsigned)__builtin_amdgcn_cvt_pk_fp8_f32(a, b, (int)old, HI);
}

// async global->LDS, 16B per lane (dest = wave-uniform base + lane*16)
__device__ __forceinline__ void gld_lds16(const void* g, void* l) {
    __builtin_amdgcn_global_load_lds(
        (__attribute__((address_space(1))) void*)(g),
        (__attribute__((address_space(3))) void*)(l), 16, 0, 0);
}

// ---------------- kernel 1: fused prep = codebook norms + fp8(x512) fragment image ----------
// wave per code (2 codes/wave): lane l holds dims 4l..4l+3. Norm: 64-lane shfl reduce
// (same tree as old cnorm -> bitwise-identical cn2). Image: lane packs 4 fp8 bytes into
// one u32 (same pk8 calls as old cbimg -> identical bytes), granules assembled via shfl:
// granule(sp,q) = u32s {sp*16+q*2, +1, sp*16+8+q*2, +1}; gid = T*512 + ph*64 + q*16 + (c&15),
// ph = sp*2 + ((c>>4)&1), T = c>>5.  (Layout identical to round-9 cbimg.)
__global__ __launch_bounds__(256) void prep_kernel(const float* __restrict__ cb,
                                                   float* __restrict__ cn2,
                                                   unsigned char* __restrict__ img) {
    const int t = threadIdx.x, w = t >> 6, lane = t & 63;
#pragma unroll
    for (int u = 0; u < 2; ++u) {
        const int c = blockIdx.x * 8 + w * 2 + u;
        float4 v = ((const float4*)cb)[c * 64 + lane];
        float s = v.x * v.x + v.y * v.y + v.z * v.z + v.w * v.w;
#pragma unroll
        for (int m = 1; m < 64; m <<= 1) s += __shfl_xor(s, m);
        if (lane == 0) cn2[c] = s;
        unsigned pw = pk8<false>(512.f * v.x, 512.f * v.y, 0);
        pw = pk8<true>(512.f * v.z, 512.f * v.w, pw);
        const int sp = (lane & 15) >> 2, q = lane & 3;
        unsigned u0 = (unsigned)__shfl((int)pw, sp * 16 + q * 2);
        unsigned u1 = (unsigned)__shfl((int)pw, sp * 16 + q * 2 + 1);
        unsigned u2 = (unsigned)__shfl((int)pw, sp * 16 + 8 + q * 2);
        unsigned u3 = (unsigned)__shfl((int)pw, sp * 16 + 8 + q * 2 + 1);
        if (lane < 16) {
            int T = c >> 5, ph = sp * 2 + ((c >> 4) & 1);
            int gid = T * 512 + ph * 64 + q * 16 + (c & 15);
            uint4 o; o.x = u0; o.y = u1; o.z = u2; o.w = u3;
            ((uint4*)img)[gid] = o;
        }
    }
}

// ---------------- kernel 2: fused VQ — 4-wave blocks, LDS-shared B, 16 waves/CU ----------
// 1024 blocks x 256 thr, 16 tokens/wave (64/block). A = fp8(-64*z) in regs (16 VGPR).
// B: triple-buffered 8KB tiles via global_load_lds (2 loads/wave/tile), counted vmcnt(2),
// raw barriers. Score math bitwise-identical to round 9.
__global__ __launch_bounds__(256, 4) void fused_vq_kernel(
        const float* __restrict__ z, const unsigned char* __restrict__ cbimg,
        const float* __restrict__ cb, const float* __restrict__ cn2,
        float* __restrict__ out, float* __restrict__ partials) {
    __shared__ char  Bs[3][8192];                 // 3 x 8KB B tiles
    __shared__ float cnS[N_EMB];                  // 4KB
    __shared__ int   winS[64];
    __shared__ float distS[64];
    __shared__ float xnS[64];
    const int t = threadIdx.x;
    const int lane = t & 63, w = t >> 6;
    const int col = lane & 15, g = lane >> 4;

    const char* srcL = (const char*)cbimg + w * 2048 + lane * 16;
    char* q0 = &Bs[0][0] + w * 2048;              // wave quarter of each buffer
    char* q1 = &Bs[1][0] + w * 2048;
    char* q2 = &Bs[2][0] + w * 2048;

    // prologue: issue tiles 0 and 1 (2 loads per wave each)
    gld_lds16(srcL,        q0);
    gld_lds16(srcL + 1024, q0 + 1024);
    gld_lds16(srcL + 8192,        q1);
    gld_lds16(srcL + 8192 + 1024, q1 + 1024);

    // A: 16 tokens/wave as fp8(-64*z); xn in fp32 (same fma order as round 9)
    long  ah[8];
    float xnp = 0.f;
    const int row = blockIdx.x * 64 + w * 16 + col;
#pragma unroll
    for (int s = 0; s < 8; ++s) {
        const float* p = z + (size_t)row * DIM + s * 32 + g * 8;
        float4 x0 = *(const float4*)p;
        float4 x1 = *(const float4*)(p + 4);
        xnp = fmaf(x0.x, x0.x, xnp); xnp = fmaf(x0.y, x0.y, xnp);
        xnp = fmaf(x0.z, x0.z, xnp); xnp = fmaf(x0.w, x0.w, xnp);
        xnp = fmaf(x1.x, x1.x, xnp); xnp = fmaf(x1.y, x1.y, xnp);
        xnp = fmaf(x1.z, x1.z, xnp); xnp = fmaf(x1.w, x1.w, xnp);
        unsigned w0, w1;
        w0 = pk8<false>(-64.f * x0.x, -64.f * x0.y, 0);
        w0 = pk8<true> (-64.f * x0.z, -64.f * x0.w, w0);
        w1 = pk8<false>(-64.f * x1.x, -64.f * x1.y, 0);
        w1 = pk8<true> (-64.f * x1.z, -64.f * x1.w, w1);
        ah[s] = (long)((((unsigned long long)w1) << 32) | w0);
    }
    xnp += __shfl_xor(xnp, 16);
    xnp += __shfl_xor(xnp, 32);
    if (g == 0) xnS[w * 16 + col] = xnp;
#pragma unroll
    for (int i = 0; i < 4; ++i) cnS[t + i * 256] = cn2[t + i * 256];

    float best[4];
    int   bidx[4];
#pragma unroll
    for (int r = 0; r < 4; ++r) { best[r] = FLT_MAX; bidx[r] = 0; }

    // make cnS/xnS ds_writes visible before the first raw barrier
    asm volatile("s_waitcnt lgkmcnt(0)" ::: "memory");

    const char* rd0 = &Bs[0][0];
    const char* rd1 = &Bs[1][0];
    const char* rd2 = &Bs[2][0];
    char *wq0 = q0, *wq1 = q1, *wq2 = q2;

    for (int T = 0; T < 32; ++T) {
        if (T < 31) asm volatile("s_waitcnt vmcnt(2)" ::: "memory");
        else        asm volatile("s_waitcnt vmcnt(0)" ::: "memory");
        __builtin_amdgcn_s_barrier();             // all waves: tile T resident
        __builtin_amdgcn_sched_barrier(0);
        if (T + 2 < 32) {                         // issue tile T+2 (buffer read at T-1)
            const char* s2 = srcL + (T + 2) * 8192;
            gld_lds16(s2,        wq2);
            gld_lds16(s2 + 1024, wq2 + 1024);
        }
        const f32x4 zero4 = {0.f, 0.f, 0.f, 0.f};
        f32x4 a0 = zero4, a1 = zero4;
        __builtin_amdgcn_s_setprio(1);
#pragma unroll
        for (int sp = 0; sp < 4; ++sp) {
            long2 b0 = *(const long2*)(rd0 + (sp * 2 + 0) * 1024 + (lane << 4));
            long2 b1 = *(const long2*)(rd0 + (sp * 2 + 1) * 1024 + (lane << 4));
            a0 = __builtin_amdgcn_mfma_f32_16x16x32_fp8_fp8(ah[2*sp],   b0.x, a0, 0, 0, 0);
            a0 = __builtin_amdgcn_mfma_f32_16x16x32_fp8_fp8(ah[2*sp+1], b0.y, a0, 0, 0, 0);
            a1 = __builtin_amdgcn_mfma_f32_16x16x32_fp8_fp8(ah[2*sp],   b1.x, a1, 0, 0, 0);
            a1 = __builtin_amdgcn_mfma_f32_16x16x32_fp8_fp8(ah[2*sp+1], b1.y, a1, 0, 0, 0);
        }
        __builtin_amdgcn_s_setprio(0);
        // score = cn + acc * 2^-14 ; nf=0 (codes +col) then nf=1 (codes +16+col), same as r9
        {
            int   code0 = T * 32 + col;
            float cn0 = cnS[code0];
            int   code1 = code0 + 16;
            float cn1 = cnS[code1];
#pragma unroll
            for (int r = 0; r < 4; ++r) {
                float s0 = fmaf(a0[r], 6.103515625e-05f, cn0);
                if (s0 < best[r]) { best[r] = s0; bidx[r] = code0; }
                float s1 = fmaf(a1[r], 6.103515625e-05f, cn1);
                if (s1 < best[r]) { best[r] = s1; bidx[r] = code1; }
            }
        }
        // rotate buffers
        const char* tr = rd0; rd0 = rd1; rd1 = rd2; rd2 = tr;
        char* tw = wq0; wq0 = wq1; wq1 = wq2; wq2 = tw;
    }

    // merge across the 16 col-lanes; token = w*16 + g*4 + r
#pragma unroll
    for (int r = 0; r < 4; ++r) {
        float sc = best[r];
        int   cd = bidx[r];
#pragma unroll
        for (int mask = 1; mask <= 8; mask <<= 1) {
            float os = __shfl_xor(sc, mask);
            int   oc = __shfl_xor(cd, mask);
            if (os < sc || (os == sc && oc < cd)) { sc = os; cd = oc; }
        }
        if (col == 0) {
            int tl = w * 16 + g * 4 + r;
            winS[tl]  = cd;
            distS[tl] = sc;
        }
    }
    __syncthreads();

    // tail A: block loss partial = sum over 64 tokens of (xn + score_win)
    if (t < 64) {
        float s = xnS[t] + distS[t];
#pragma unroll
        for (int m = 1; m < 64; m <<= 1) s += __shfl_xor(s, m);
        if (t == 0) partials[blockIdx.x] = s;
    }
    // tail B: output = codebook[winner]; wave-uniform row reads, coalesced writes
    const size_t ob = (size_t)blockIdx.x * 4096;  // float4 units
#pragma unroll 4
    for (int i = 0; i < 16; ++i) {
        int f = i * 256 + t;
        int tl = f >> 6, c4 = f & 63;
        float4 qv = ((const float4*)cb)[winS[tl] * 64 + c4];
        ((float4*)out)[ob + f] = qv;
    }
}

// ---------------- kernel 3: deterministic partial reduction (1024 partials) ----------------
__global__ __launch_bounds__(256) void reduce_kernel(const float* __restrict__ partials,
                                                     float* __restrict__ out_loss) {
    const int tid = threadIdx.x;
    float s = 0.f;
#pragma unroll
    for (int u = 0; u < 4; ++u) s += partials[tid + 256 * u];
#pragma unroll
    for (int m = 1; m < 64; m <<= 1) s += __shfl_xor(s, m);
    __shared__ float wsum[4];
    if ((tid & 63) == 0) wsum[tid >> 6] = s;
    __syncthreads();
    if (tid == 0) *out_loss = 2.0f * ((wsum[0] + wsum[1]) + (wsum[2] + wsum[3]));
}

extern "C" void kernel_launch(void* const* d_in, const int* in_sizes, int n_in,
                              void* d_out, int out_size, void* d_ws, size_t ws_size,
                              hipStream_t stream) {
    const float* z  = (const float*)d_in[0];   // z_e       [65536,256]
    const float* cb = (const float*)d_in[1];   // codebook  [1024,256]
    float* out = (float*)d_out;
    char*  ws  = (char*)d_ws;

    float*         cn2      = (float*)(ws);                    // 4 KB
    float*         partials = (float*)(ws + 4096);             // 4 KB
    unsigned char* cbimg    = (unsigned char*)(ws + 8192);     // 256 KB

    prep_kernel    <<<128, 256, 0, stream>>>(cb, cn2, cbimg);
    fused_vq_kernel<<<1024, 256, 0, stream>>>(z, cbimg, cb, cn2, out, partials);
    reduce_kernel  <<<1, 256, 0, stream>>>(partials, out + (size_t)N_TOKENS * DIM);
}

// Round 11
// 50.810 us; speedup vs baseline: 1.2929x; 1.0581x over previous
//
#include <hip/hip_runtime.h>
#include <float.h>
#include <stdint.h>

#define N_TOKENS 65536
#define N_EMB    1024
#define DIM      256

typedef __attribute__((ext_vector_type(4))) int int4v;

// async global->LDS, 16B per lane (dest = wave-uniform base + lane*16)
__device__ __forceinline__ void gld_lds16(const void* g, void* l) {
    __builtin_amdgcn_global_load_lds(
        (__attribute__((address_space(1))) void*)(g),
        (__attribute__((address_space(3))) void*)(l), 16, 0, 0);
}

// ---------------- kernel 1: fused prep = norms (f32 + x2^20 int) + i8(x2^17) image ----------
// wave per 2 codes: lane l holds dims 4l..4l+3. Image granule (16B) for MFMA 16x16x64:
// tile T (32 codes), phase ph = ks*2 + half (ks = K-step of 64 dims, half = code>>4 bit):
// compute-lane l reads code (ph&1)*16+(l&15), dims (ph>>1)*64 + (l>>4)*16 + 0..15.
// Assembly via shfl: write-lane L<16 (ks=L>>2, g=L&3) gathers u32 q from src-lane
// ks*16 + g*4 + q. Granule gid = T*512 + ph*64 + g*16 + (c&15).
__global__ __launch_bounds__(256) void prep_kernel(const float* __restrict__ cb,
                                                   float* __restrict__ cn2,
                                                   int* __restrict__ cnI,
                                                   unsigned char* __restrict__ img) {
    const int t = threadIdx.x, w = t >> 6, lane = t & 63;
#pragma unroll
    for (int u = 0; u < 2; ++u) {
        const int c = blockIdx.x * 8 + w * 2 + u;
        float4 v = ((const float4*)cb)[c * 64 + lane];
        float s = v.x * v.x + v.y * v.y + v.z * v.z + v.w * v.w;
#pragma unroll
        for (int m = 1; m < 64; m <<= 1) s += __shfl_xor(s, m);
        if (lane == 0) { cn2[c] = s; cnI[c] = (int)rintf(s * 1048576.f); }
        int a0 = (int)fminf(fmaxf(rintf(v.x * 131072.f), -127.f), 127.f);
        int a1 = (int)fminf(fmaxf(rintf(v.y * 131072.f), -127.f), 127.f);
        int a2 = (int)fminf(fmaxf(rintf(v.z * 131072.f), -127.f), 127.f);
        int a3 = (int)fminf(fmaxf(rintf(v.w * 131072.f), -127.f), 127.f);
        unsigned pw = (a0 & 255) | ((a1 & 255) << 8) | ((a2 & 255) << 16) | ((a3 & 255) << 24);
        int src = (lane >> 2) * 16 + (lane & 3) * 4;
        unsigned u0 = (unsigned)__shfl((int)pw, src + 0);
        unsigned u1 = (unsigned)__shfl((int)pw, src + 1);
        unsigned u2 = (unsigned)__shfl((int)pw, src + 2);
        unsigned u3 = (unsigned)__shfl((int)pw, src + 3);
        if (lane < 16) {
            int ks = lane >> 2, g = lane & 3;
            int T = c >> 5, half = (c >> 4) & 1;
            int gid = T * 512 + (ks * 2 + half) * 64 + g * 16 + (c & 15);
            uint4 o; o.x = u0; o.y = u1; o.z = u2; o.w = u3;
            ((uint4*)img)[gid] = o;
        }
    }
}

// ---------------- kernel 2: fused VQ — i8 MFMA (K=64), 32 tok/wave, 3-buf pipeline ----------
// 512 blocks x 256 thr (4 waves). A = i8(16*z) in regs (32 VGPR). B tiles 8KB via
// global_load_lds, counted vmcnt(2), raw barriers. Argmin = integer MAX of
// accI' = 2^21*dot - round(cn*2^20)  (cn folded into MFMA acc init).
__global__ __launch_bounds__(256, 2) void fused_vq_kernel(
        const float* __restrict__ z, const unsigned char* __restrict__ cbimg,
        const float* __restrict__ cb, const float* __restrict__ cn2,
        const int* __restrict__ cnI,
        float* __restrict__ out, float* __restrict__ partials) {
    __shared__ char  Bs[3][8192];                 // 3 x 8KB B tiles
    __shared__ float cnS[N_EMB];                  // 4KB (float norms, for loss)
    __shared__ int   cnIS[N_EMB];                 // 4KB (int keys)
    __shared__ int   winS[128];
    __shared__ float distS[128];
    __shared__ float xnS[128];
    const int t = threadIdx.x;
    const int lane = t & 63, w = t >> 6;
    const int col = lane & 15, g = lane >> 4;

    const char* srcL = (const char*)cbimg + w * 2048 + lane * 16;
    char* q0 = &Bs[0][0] + w * 2048;              // wave quarter of each buffer
    char* q1 = &Bs[1][0] + w * 2048;
    char* q2 = &Bs[2][0] + w * 2048;

    // prologue: issue tiles 0 and 1 (2 loads per wave each)
    gld_lds16(srcL,        q0);
    gld_lds16(srcL + 1024, q0 + 1024);
    gld_lds16(srcL + 8192,        q1);
    gld_lds16(srcL + 8192 + 1024, q1 + 1024);

    // A: 32 tokens/wave as i8(16*z) (truncating cvt); xn exact fp32
    int4v ah[2][4];
    float xnp[2] = {0.f, 0.f};
    const int rbase = blockIdx.x * 128 + w * 32 + col;
#pragma unroll
    for (int m = 0; m < 2; ++m) {
#pragma unroll
        for (int ks = 0; ks < 4; ++ks) {
            const float* p = z + (size_t)(rbase + m * 16) * DIM + ks * 64 + g * 16;
            float4 x0 = *(const float4*)p;
            float4 x1 = *(const float4*)(p + 4);
            float4 x2 = *(const float4*)(p + 8);
            float4 x3 = *(const float4*)(p + 12);
            xnp[m] = fmaf(x0.x, x0.x, xnp[m]); xnp[m] = fmaf(x0.y, x0.y, xnp[m]);
            xnp[m] = fmaf(x0.z, x0.z, xnp[m]); xnp[m] = fmaf(x0.w, x0.w, xnp[m]);
            xnp[m] = fmaf(x1.x, x1.x, xnp[m]); xnp[m] = fmaf(x1.y, x1.y, xnp[m]);
            xnp[m] = fmaf(x1.z, x1.z, xnp[m]); xnp[m] = fmaf(x1.w, x1.w, xnp[m]);
            xnp[m] = fmaf(x2.x, x2.x, xnp[m]); xnp[m] = fmaf(x2.y, x2.y, xnp[m]);
            xnp[m] = fmaf(x2.z, x2.z, xnp[m]); xnp[m] = fmaf(x2.w, x2.w, xnp[m]);
            xnp[m] = fmaf(x3.x, x3.x, xnp[m]); xnp[m] = fmaf(x3.y, x3.y, xnp[m]);
            xnp[m] = fmaf(x3.z, x3.z, xnp[m]); xnp[m] = fmaf(x3.w, x3.w, xnp[m]);
            int4v fr;
#pragma unroll
            for (int q = 0; q < 4; ++q) {
                const float4& xq = q == 0 ? x0 : (q == 1 ? x1 : (q == 2 ? x2 : x3));
                int b0 = (int)(xq.x * 16.f), b1 = (int)(xq.y * 16.f);
                int b2 = (int)(xq.z * 16.f), b3 = (int)(xq.w * 16.f);
                fr[q] = (b0 & 255) | ((b1 & 255) << 8) | ((b2 & 255) << 16) | ((b3 & 255) << 24);
            }
            ah[m][ks] = fr;
        }
    }
    xnp[0] += __shfl_xor(xnp[0], 16); xnp[0] += __shfl_xor(xnp[0], 32);
    xnp[1] += __shfl_xor(xnp[1], 16); xnp[1] += __shfl_xor(xnp[1], 32);
    if (g == 0) { xnS[w * 32 + col] = xnp[0]; xnS[w * 32 + 16 + col] = xnp[1]; }
#pragma unroll
    for (int i = 0; i < 4; ++i) {
        cnS[t + i * 256]  = cn2[t + i * 256];
        cnIS[t + i * 256] = cnI[t + i * 256];
    }

    int best[2][4], bidx[2][4];
#pragma unroll
    for (int m = 0; m < 2; ++m)
#pragma unroll
        for (int r = 0; r < 4; ++r) { best[m][r] = INT32_MIN; bidx[m][r] = 0; }

    asm volatile("s_waitcnt lgkmcnt(0)" ::: "memory");  // cnS/cnIS/xnS visible

    const char* rd0 = &Bs[0][0];
    const char* rd1 = &Bs[1][0];
    const char* rd2 = &Bs[2][0];
    char *wq0 = q0, *wq1 = q1, *wq2 = q2;

    for (int T = 0; T < 32; ++T) {
        if (T < 31) asm volatile("s_waitcnt vmcnt(2)" ::: "memory");
        else        asm volatile("s_waitcnt vmcnt(0)" ::: "memory");
        __builtin_amdgcn_s_barrier();             // all waves: tile T resident
        __builtin_amdgcn_sched_barrier(0);
        if (T + 2 < 32) {                         // issue tile T+2 (buffer read at T-1)
            const char* s2 = srcL + (T + 2) * 8192;
            gld_lds16(s2,        wq2);
            gld_lds16(s2 + 1024, wq2 + 1024);
        }
        const int code0 = T * 32 + col;
        const int code1 = code0 + 16;
        const int c0I = cnIS[code0], c1I = cnIS[code1];
        int4v a00 = {-c0I, -c0I, -c0I, -c0I};
        int4v a01 = {-c1I, -c1I, -c1I, -c1I};
        int4v a10 = a00, a11 = a01;
        __builtin_amdgcn_s_setprio(1);
#pragma unroll
        for (int ks = 0; ks < 4; ++ks) {
            int4v b0 = *(const int4v*)(rd0 + (ks * 2 + 0) * 1024 + (lane << 4));
            int4v b1 = *(const int4v*)(rd0 + (ks * 2 + 1) * 1024 + (lane << 4));
            a00 = __builtin_amdgcn_mfma_i32_16x16x64_i8(ah[0][ks], b0, a00, 0, 0, 0);
            a10 = __builtin_amdgcn_mfma_i32_16x16x64_i8(ah[1][ks], b0, a10, 0, 0, 0);
            a01 = __builtin_amdgcn_mfma_i32_16x16x64_i8(ah[0][ks], b1, a01, 0, 0, 0);
            a11 = __builtin_amdgcn_mfma_i32_16x16x64_i8(ah[1][ks], b1, a11, 0, 0, 0);
        }
        __builtin_amdgcn_s_setprio(0);
        // integer argmin: maximize accI' (codes visited ascending -> first-min tie-break)
#pragma unroll
        for (int r = 0; r < 4; ++r) {
            if (a00[r] > best[0][r]) { best[0][r] = a00[r]; bidx[0][r] = code0; }
            if (a01[r] > best[0][r]) { best[0][r] = a01[r]; bidx[0][r] = code1; }
            if (a10[r] > best[1][r]) { best[1][r] = a10[r]; bidx[1][r] = code0; }
            if (a11[r] > best[1][r]) { best[1][r] = a11[r]; bidx[1][r] = code1; }
        }
        // rotate buffers
        const char* tr = rd0; rd0 = rd1; rd1 = rd2; rd2 = tr;
        char* tw = wq0; wq0 = wq1; wq1 = wq2; wq2 = tw;
    }

    // merge across the 16 col-lanes; token = w*32 + m*16 + g*4 + r
#pragma unroll
    for (int m = 0; m < 2; ++m)
#pragma unroll
        for (int r = 0; r < 4; ++r) {
            int a  = best[m][r];
            int cd = bidx[m][r];
#pragma unroll
            for (int mask = 1; mask <= 8; mask <<= 1) {
                int oa = __shfl_xor(a, mask);
                int oc = __shfl_xor(cd, mask);
                if (oa > a || (oa == a && oc < cd)) { a = oa; cd = oc; }
            }
            if (col == 0) {
                int tl = w * 32 + m * 16 + g * 4 + r;
                winS[tl] = cd;
                // score = cn - 2*dot = cn - (accI' + cnI)*2^-20
                distS[tl] = fmaf((float)(a + cnIS[cd]), -9.5367431640625e-07f, cnS[cd]);
            }
        }
    __syncthreads();

    // tail A: block loss partial = sum over 128 tokens of (xn + score_win)
    if (t < 64) {
        float s = (xnS[t] + distS[t]) + (xnS[t + 64] + distS[t + 64]);
#pragma unroll
        for (int m = 1; m < 64; m <<= 1) s += __shfl_xor(s, m);
        if (t == 0) partials[blockIdx.x] = s;
    }
    // tail B: output = codebook[winner]; wave-uniform row reads, coalesced writes
    const size_t ob = (size_t)blockIdx.x * 8192;  // float4 units
#pragma unroll 4
    for (int i = 0; i < 32; ++i) {
        int f = i * 256 + t;
        int tl = f >> 6, c4 = f & 63;
        float4 qv = ((const float4*)cb)[winS[tl] * 64 + c4];
        ((float4*)out)[ob + f] = qv;
    }
}

// ---------------- kernel 3: deterministic partial reduction (512 partials) ----------------
__global__ __launch_bounds__(256) void reduce_kernel(const float* __restrict__ partials,
                                                     float* __restrict__ out_loss) {
    const int tid = threadIdx.x;
    float s = partials[tid] + partials[tid + 256];
#pragma unroll
    for (int m = 1; m < 64; m <<= 1) s += __shfl_xor(s, m);
    __shared__ float wsum[4];
    if ((tid & 63) == 0) wsum[tid >> 6] = s;
    __syncthreads();
    if (tid == 0) *out_loss = 2.0f * ((wsum[0] + wsum[1]) + (wsum[2] + wsum[3]));
}

extern "C" void kernel_launch(void* const* d_in, const int* in_sizes, int n_in,
                              void* d_out, int out_size, void* d_ws, size_t ws_size,
                              hipStream_t stream) {
    const float* z  = (const float*)d_in[0];   // z_e       [65536,256]
    const float* cb = (const float*)d_in[1];   // codebook  [1024,256]
    float* out = (float*)d_out;
    char*  ws  = (char*)d_ws;

    float*         cn2      = (float*)(ws);                    // 4 KB
    int*           cnI      = (int*)(ws + 4096);               // 4 KB
    float*         partials = (float*)(ws + 8192);             // 2 KB
    unsigned char* cbimg    = (unsigned char*)(ws + 16384);    // 256 KB

    prep_kernel    <<<128, 256, 0, stream>>>(cb, cn2, cnI, cbimg);
    fused_vq_kernel<<<512, 256, 0, stream>>>(z, cbimg, cb, cn2, cnI, out, partials);
    reduce_kernel  <<<1, 256, 0, stream>>>(partials, out + (size_t)N_TOKENS * DIM);
}